// Round 2
// baseline (6465.801 us; speedup 1.0000x reference)
//
#include <hip/hip_runtime.h>
#include <hip/hip_bf16.h>

// MPNN on MI355X.
// msg[e,o] = sum_k t[e,k]*Q[src,k,o] + q0[src,o],  Q'[n] = h[n] @ W2ext
// W2ext[i][k*32+o] = en_W2[k][i*32+o]; cols 1024..1055 hold b2 (per-node bias term q0).
// Q' stored bf16 [CH,1056] in a node-chunked buffer sized to ws_size; edges bucketed by
// src-chunk once (src static across the 3 steps).

#define NN 100000
#define NE 320000
#define DD 32
#define QC 1056   // 33*32 (32 k-blocks + 1 bias block)

__device__ __forceinline__ float bf2f(unsigned short u) {
    return __uint_as_float(((unsigned int)u) << 16);
}
__device__ __forceinline__ unsigned short f2bf(float f) {
    unsigned int x = __float_as_uint(f);
    unsigned int r = (x + 0x7fffu + ((x >> 16) & 1u)) >> 16;
    return (unsigned short)r;
}
__device__ __forceinline__ unsigned int pack2(float lo, float hi) {
    return (unsigned int)f2bf(lo) | ((unsigned int)f2bf(hi) << 16);
}

// ---- build W2ext [32][1056]
__global__ __launch_bounds__(256) void k_w2ext(const float* __restrict__ W2,
                                               const float* __restrict__ b2,
                                               float* __restrict__ W2ext) {
    int idx = blockIdx.x * 256 + threadIdx.x;
    if (idx >= 32 * QC) return;
    int i = idx / QC, c = idx % QC;
    float v;
    if (c < 1024) { int k = c >> 5, o = c & 31; v = W2[k * 1024 + i * 32 + o]; }
    else          { v = b2[i * 32 + (c - 1024)]; }
    W2ext[idx] = v;
}

// ---- node encoder + projection
__global__ __launch_bounds__(256) void k_node_enc(
    const int* __restrict__ nfeats, const float* __restrict__ emb,
    const float* __restrict__ encW, const float* __restrict__ encB,
    const float* __restrict__ projW, const float* __restrict__ projB,
    float* __restrict__ h) {
    __shared__ float sEncW[1024], sProjW[1024], sEncB[32], sProjB[32];
    __shared__ float sEmb[8][33], sNh[8][33];
    int tid = threadIdx.x;
    for (int i = tid; i < 1024; i += 256) { sEncW[i] = encW[i]; sProjW[i] = projW[i]; }
    if (tid < 32) { sEncB[tid] = encB[tid]; sProjB[tid] = projB[tid]; }
    int ln = tid >> 5, o = tid & 31;
    int node = blockIdx.x * 8 + ln;
    int nt = nfeats[node];
    sEmb[ln][o] = fmaxf(emb[nt * DD + o], 0.f);
    __syncthreads();
    float acc = sEncB[o];
    #pragma unroll
    for (int i = 0; i < 32; ++i) acc += sEmb[ln][i] * sEncW[i * 32 + o];
    sNh[ln][o] = fmaxf(acc, 0.f);
    __syncthreads();
    float acc2 = sProjB[o];
    #pragma unroll
    for (int i = 0; i < 32; ++i) acc2 += sNh[ln][i] * sProjW[i * 32 + o];
    h[node * DD + o] = fmaxf(acc2, 0.f);
}

// ---- edge encoder
__global__ __launch_bounds__(256) void k_edge_t(
    const float* __restrict__ efeats,
    const float* __restrict__ eencW, const float* __restrict__ eencB,
    const float* __restrict__ enW1, const float* __restrict__ enB1,
    float* __restrict__ t) {
    __shared__ float sEW[512], sW1[1024], sEB[32], sB1[32];
    __shared__ float sEf[8][17], sEh[8][33];
    int tid = threadIdx.x;
    for (int i = tid; i < 512; i += 256) sEW[i] = eencW[i];
    for (int i = tid; i < 1024; i += 256) sW1[i] = enW1[i];
    if (tid < 32) { sEB[tid] = eencB[tid]; sB1[tid] = enB1[tid]; }
    int ln = tid >> 5, o = tid & 31;
    int e = blockIdx.x * 8 + ln;
    if (o < 16) sEf[ln][o] = efeats[e * 16 + o];
    __syncthreads();
    float acc = sEB[o];
    #pragma unroll
    for (int i = 0; i < 16; ++i) acc += sEf[ln][i] * sEW[i * 32 + o];
    sEh[ln][o] = acc;
    __syncthreads();
    float acc2 = sB1[o];
    #pragma unroll
    for (int i = 0; i < 32; ++i) acc2 += sEh[ln][i] * sW1[i * 32 + o];
    t[e * 32 + o] = fmaxf(acc2, 0.f);
}

// ---- edge bucketing by src-chunk (run once; src static)
__global__ __launch_bounds__(256) void k_hist(const int* __restrict__ src,
                                              int* __restrict__ counts, int CH) {
    int e = blockIdx.x * 256 + threadIdx.x;
    if (e < NE) atomicAdd(&counts[src[e] / CH], 1);
}
__global__ void k_scan(const int* __restrict__ counts, int* __restrict__ offs,
                       int* __restrict__ cursor, int NC) {
    if (threadIdx.x == 0) {
        int s = 0;
        for (int c = 0; c < NC; ++c) { offs[c] = s; cursor[c] = s; s += counts[c]; }
        offs[NC] = s;
    }
}
__global__ __launch_bounds__(256) void k_scatter(const int* __restrict__ src,
                                                 int* __restrict__ cursor,
                                                 int* __restrict__ eperm, int CH) {
    int e = blockIdx.x * 256 + threadIdx.x;
    if (e < NE) {
        int pos = atomicAdd(&cursor[src[e] / CH], 1);
        eperm[pos] = e;
    }
}

// ---- Q for a node chunk: Q[n-nodeBase, c] = sum_i h[n,i]*W2ext[i,c]  (bf16)
// 256 threads = 128 nodes/block (2 per thread-quad), 8 cols/thread/colgroup.
__global__ __launch_bounds__(256) void k_Q(
    const float* __restrict__ h, const float* __restrict__ W2ext,
    unsigned short* __restrict__ Q, int nodeBase, int nodeEnd) {
    __shared__ float sW[32 * 36];
    int tid = threadIdx.x;
    int m2 = tid >> 2, l4 = tid & 3;
    int n0 = nodeBase + blockIdx.x * 128 + m2;
    int n1 = n0 + 64;
    bool a0 = n0 < nodeEnd, a1 = n1 < nodeEnd;
    float h0[32], h1[32];
    if (a0) {
        const float* hp = h + (size_t)n0 * 32;
        #pragma unroll
        for (int i4 = 0; i4 < 8; ++i4) {
            float4 v = *(const float4*)(hp + i4 * 4);
            h0[i4*4] = v.x; h0[i4*4+1] = v.y; h0[i4*4+2] = v.z; h0[i4*4+3] = v.w;
        }
    } else {
        #pragma unroll
        for (int i = 0; i < 32; ++i) h0[i] = 0.f;
    }
    if (a1) {
        const float* hp = h + (size_t)n1 * 32;
        #pragma unroll
        for (int i4 = 0; i4 < 8; ++i4) {
            float4 v = *(const float4*)(hp + i4 * 4);
            h1[i4*4] = v.x; h1[i4*4+1] = v.y; h1[i4*4+2] = v.z; h1[i4*4+3] = v.w;
        }
    } else {
        #pragma unroll
        for (int i = 0; i < 32; ++i) h1[i] = 0.f;
    }
    unsigned short* q0 = Q + (size_t)(n0 - nodeBase) * QC + l4 * 8;
    unsigned short* q1 = Q + (size_t)(n1 - nodeBase) * QC + l4 * 8;
    for (int cg = 0; cg < 33; ++cg) {
        __syncthreads();
        for (int idx = tid; idx < 1024; idx += 256) {
            int i = idx >> 5, c = idx & 31;
            sW[i * 36 + c] = W2ext[i * QC + cg * 32 + c];
        }
        __syncthreads();
        float acc0[8], acc1[8];
        #pragma unroll
        for (int j = 0; j < 8; ++j) { acc0[j] = 0.f; acc1[j] = 0.f; }
        const float* wp = sW + l4 * 8;
        #pragma unroll 8
        for (int i = 0; i < 32; ++i) {
            float4 wa = *(const float4*)(wp + i * 36);
            float4 wb = *(const float4*)(wp + i * 36 + 4);
            float x0 = h0[i], x1 = h1[i];
            acc0[0] += x0 * wa.x; acc0[1] += x0 * wa.y; acc0[2] += x0 * wa.z; acc0[3] += x0 * wa.w;
            acc0[4] += x0 * wb.x; acc0[5] += x0 * wb.y; acc0[6] += x0 * wb.z; acc0[7] += x0 * wb.w;
            acc1[0] += x1 * wa.x; acc1[1] += x1 * wa.y; acc1[2] += x1 * wa.z; acc1[3] += x1 * wa.w;
            acc1[4] += x1 * wb.x; acc1[5] += x1 * wb.y; acc1[6] += x1 * wb.z; acc1[7] += x1 * wb.w;
        }
        if (a0) {
            uint4 v; v.x = pack2(acc0[0], acc0[1]); v.y = pack2(acc0[2], acc0[3]);
            v.z = pack2(acc0[4], acc0[5]); v.w = pack2(acc0[6], acc0[7]);
            *(uint4*)(q0 + cg * 32) = v;
        }
        if (a1) {
            uint4 v; v.x = pack2(acc1[0], acc1[1]); v.y = pack2(acc1[2], acc1[3]);
            v.z = pack2(acc1[4], acc1[5]); v.w = pack2(acc1[6], acc1[7]);
            *(uint4*)(q1 + cg * 32) = v;
        }
    }
}

// ---- msg + scatter for one chunk's edge bucket
__global__ __launch_bounds__(256) void k_msgQ(
    const float* __restrict__ t, const int* __restrict__ src, const int* __restrict__ dst,
    const int* __restrict__ eperm, const int* __restrict__ offs, int chunk, int nodeBase,
    const unsigned short* __restrict__ Q, float* __restrict__ agg) {
    __shared__ float sT[32][33];
    __shared__ int sRow[32], sDst[32], sEdge[32];
    int beg = offs[chunk], end = offs[chunk + 1];
    int tid = threadIdx.x;
    for (int s0 = beg + blockIdx.x * 32; s0 < end; s0 += gridDim.x * 32) {
        int nact = min(32, end - s0);
        __syncthreads();
        if (tid < 32) {
            int e = (tid < nact) ? eperm[s0 + tid] : -1;
            sEdge[tid] = e;
            sRow[tid] = (e >= 0) ? (src[e] - nodeBase) : 0;
            sDst[tid] = (e >= 0) ? dst[e] : -1;
        }
        __syncthreads();
        for (int idx = tid; idx < (nact << 3); idx += 256) {
            int el = idx >> 3, c4 = (idx & 7) * 4;
            float4 tv = *(const float4*)(t + (size_t)sEdge[el] * 32 + c4);
            sT[el][c4] = tv.x; sT[el][c4+1] = tv.y; sT[el][c4+2] = tv.z; sT[el][c4+3] = tv.w;
        }
        __syncthreads();
        int el = tid >> 3, l8 = tid & 7;
        if (el < nact) {
            const unsigned short* qp = Q + (size_t)sRow[el] * QC + l8 * 4;
            float a0 = 0.f, a1 = 0.f, a2 = 0.f, a3 = 0.f;
            #pragma unroll 8
            for (int k = 0; k < 32; ++k) {
                float tk = sT[el][k];
                ushort4 q = *(const ushort4*)(qp + k * 32);
                a0 += tk * bf2f(q.x); a1 += tk * bf2f(q.y);
                a2 += tk * bf2f(q.z); a3 += tk * bf2f(q.w);
            }
            ushort4 qb = *(const ushort4*)(qp + 1024);
            a0 += bf2f(qb.x); a1 += bf2f(qb.y); a2 += bf2f(qb.z); a3 += bf2f(qb.w);
            float* ap = agg + (size_t)sDst[el] * 32 + l8 * 4;
            atomicAdd(ap + 0, a0); atomicAdd(ap + 1, a1);
            atomicAdd(ap + 2, a2); atomicAdd(ap + 3, a3);
        }
    }
}

// ---- fallback msg (tiny ws): recompute We per edge
__global__ __launch_bounds__(256) void k_msgC(
    const float* __restrict__ t, const int* __restrict__ src, const int* __restrict__ dst,
    const float* __restrict__ h, const float* __restrict__ W2ext, float* __restrict__ agg) {
    __shared__ float sT[32][33], sH[32][33];
    __shared__ int sSrc[32], sDst[32];
    int tid = threadIdx.x;
    int e0 = blockIdx.x * 32;
    if (tid < 32) sSrc[tid] = src[e0 + tid];
    else if (tid < 64) sDst[tid - 32] = dst[e0 + tid - 32];
    __syncthreads();
    for (int idx = tid; idx < 1024; idx += 256) {
        int el = idx >> 5, k = idx & 31;
        sT[el][k] = t[(e0 + el) * 32 + k];
        sH[el][k] = h[(size_t)sSrc[el] * 32 + k];
    }
    __syncthreads();
    int el = tid >> 3, l8 = tid & 7;
    int c0 = l8 * 4;
    float m0 = 0.f, m1 = 0.f, m2 = 0.f, m3 = 0.f;
    for (int i = 0; i < 32; ++i) {
        const float* wrow = W2ext + i * QC;
        float4 wb = *(const float4*)(wrow + 1024 + c0);
        float w0 = wb.x, w1 = wb.y, w2 = wb.z, w3 = wb.w;
        #pragma unroll 8
        for (int k = 0; k < 32; ++k) {
            float tk = sT[el][k];
            float4 w = *(const float4*)(wrow + k * 32 + c0);
            w0 += tk * w.x; w1 += tk * w.y; w2 += tk * w.z; w3 += tk * w.w;
        }
        float hi = sH[el][i];
        m0 += hi * w0; m1 += hi * w1; m2 += hi * w2; m3 += hi * w3;
    }
    float* ap = agg + (size_t)sDst[el] * 32 + c0;
    atomicAdd(ap + 0, m0); atomicAdd(ap + 1, m1);
    atomicAdd(ap + 2, m2); atomicAdd(ap + 3, m3);
}

// ---- GRU step, 32 nodes/block (amortize 24KB weight stage)
__global__ __launch_bounds__(256) void k_gru(
    const float* __restrict__ agg, const float* __restrict__ convB,
    const float* __restrict__ Wi, const float* __restrict__ Wh,
    const float* __restrict__ bi, const float* __restrict__ bh,
    float* __restrict__ h) {
    __shared__ float sWi[3072], sWh[3072], sBi[96], sBh[96], sCb[32];
    __shared__ float sX[8][33], sH[8][33];
    int tid = threadIdx.x;
    for (int i = tid; i < 3072; i += 256) { sWi[i] = Wi[i]; sWh[i] = Wh[i]; }
    if (tid < 96) { sBi[tid] = bi[tid]; sBh[tid] = bh[tid]; }
    if (tid < 32) sCb[tid] = convB[tid];
    int ln = tid >> 5, o = tid & 31;
    for (int g = 0; g < 4; ++g) {
        int node = blockIdx.x * 32 + g * 8 + ln;
        float hv = h[node * 32 + o];
        float av = agg[node * 32 + o];
        __syncthreads();
        sX[ln][o] = fmaxf(av + sCb[o], 0.f);
        sH[ln][o] = hv;
        __syncthreads();
        float air = sBi[o], aiz = sBi[o + 32], ain = sBi[o + 64];
        float ahr = sBh[o], ahz = sBh[o + 32], ahn = sBh[o + 64];
        #pragma unroll 8
        for (int i = 0; i < 32; ++i) {
            float x = sX[ln][i], hh = sH[ln][i];
            air += x * sWi[i * 96 + o];      ahr += hh * sWh[i * 96 + o];
            aiz += x * sWi[i * 96 + o + 32]; ahz += hh * sWh[i * 96 + o + 32];
            ain += x * sWi[i * 96 + o + 64]; ahn += hh * sWh[i * 96 + o + 64];
        }
        float r = 1.f / (1.f + __expf(-(air + ahr)));
        float z = 1.f / (1.f + __expf(-(aiz + ahz)));
        float ng = tanhf(ain + r * ahn);
        h[node * 32 + o] = (1.f - z) * ng + z * hv;
    }
}

// ---- decoder
__global__ __launch_bounds__(256) void k_dec(
    const float* __restrict__ h,
    const float* __restrict__ W1, const float* __restrict__ b1, const float* __restrict__ a1,
    const float* __restrict__ W2, const float* __restrict__ b2, const float* __restrict__ a2,
    const float* __restrict__ W3, const float* __restrict__ b3, const float* __restrict__ a3,
    const float* __restrict__ W4, const float* __restrict__ b4,
    float* __restrict__ out) {
    __shared__ float sW1[1024], sW2[1024], sW3[1024], sW4[96];
    __shared__ float sB1[32], sB2[32], sB3[32], sB4[3];
    __shared__ float sYa[8][33], sYb[8][33];
    int tid = threadIdx.x;
    for (int i = tid; i < 1024; i += 256) { sW1[i] = W1[i]; sW2[i] = W2[i]; sW3[i] = W3[i]; }
    if (tid < 96) sW4[tid] = W4[tid];
    if (tid < 32) { sB1[tid] = b1[tid]; sB2[tid] = b2[tid]; sB3[tid] = b3[tid]; }
    if (tid < 3) sB4[tid] = b4[tid];
    float A1 = a1[0], A2 = a2[0], A3 = a3[0];
    int ln = tid >> 5, o = tid & 31;
    int node = blockIdx.x * 8 + ln;
    sYa[ln][o] = h[node * 32 + o];
    __syncthreads();
    float acc = sB1[o];
    #pragma unroll
    for (int i = 0; i < 32; ++i) acc += sYa[ln][i] * sW1[i * 32 + o];
    acc = acc >= 0.f ? acc : A1 * acc;
    sYb[ln][o] = acc;
    __syncthreads();
    acc = sB2[o];
    #pragma unroll
    for (int i = 0; i < 32; ++i) acc += sYb[ln][i] * sW2[i * 32 + o];
    acc = acc >= 0.f ? acc : A2 * acc;
    __syncthreads();
    sYa[ln][o] = acc;
    __syncthreads();
    acc = sB3[o];
    #pragma unroll
    for (int i = 0; i < 32; ++i) acc += sYa[ln][i] * sW3[i * 32 + o];
    acc = acc >= 0.f ? acc : A3 * acc;
    __syncthreads();
    sYb[ln][o] = acc;
    __syncthreads();
    if (o < 3) {
        float r = sB4[o];
        #pragma unroll
        for (int i = 0; i < 32; ++i) r += sYb[ln][i] * sW4[i * 3 + o];
        out[node * 3 + o] = r;
    }
}

extern "C" void kernel_launch(void* const* d_in, const int* in_sizes, int n_in,
                              void* d_out, int out_size, void* d_ws, size_t ws_size,
                              hipStream_t stream) {
    const int*   nfeats = (const int*)d_in[0];
    const float* efeats = (const float*)d_in[1];
    const int*   src    = (const int*)d_in[2];
    const int*   dst    = (const int*)d_in[3];
    const float* emb    = (const float*)d_in[4];
    const float* encW   = (const float*)d_in[5];
    const float* encB   = (const float*)d_in[6];
    const float* eencW  = (const float*)d_in[7];
    const float* eencB  = (const float*)d_in[8];
    const float* projW  = (const float*)d_in[9];
    const float* projB  = (const float*)d_in[10];
    const float* enW1   = (const float*)d_in[11];
    const float* enB1   = (const float*)d_in[12];
    const float* enW2   = (const float*)d_in[13];
    const float* enB2   = (const float*)d_in[14];
    const float* convB  = (const float*)d_in[15];
    const float* gruWi  = (const float*)d_in[16];
    const float* gruWh  = (const float*)d_in[17];
    const float* gruBi  = (const float*)d_in[18];
    const float* gruBh  = (const float*)d_in[19];
    const float* dW1 = (const float*)d_in[20]; const float* db1 = (const float*)d_in[21]; const float* da1 = (const float*)d_in[22];
    const float* dW2 = (const float*)d_in[23]; const float* db2 = (const float*)d_in[24]; const float* da2 = (const float*)d_in[25];
    const float* dW3 = (const float*)d_in[26]; const float* db3 = (const float*)d_in[27]; const float* da3 = (const float*)d_in[28];
    const float* dW4 = (const float*)d_in[29]; const float* db4 = (const float*)d_in[30];
    float* out = (float*)d_out;

    float* h     = (float*)d_ws;                       // NN*32
    float* t     = h + (size_t)NN * 32;                // NE*32
    float* agg   = t + (size_t)NE * 32;                // NN*32
    float* W2ext = agg + (size_t)NN * 32;              // 32*QC
    int* eperm   = (int*)(W2ext + 32 * QC);            // NE
    int* counts  = eperm + NE;                         // 64
    int* offs    = counts + 64;                        // 65
    int* cursor  = offs + 65;                          // 64
    size_t fixed = ((char*)(cursor + 64) - (char*)d_ws);
    fixed = (fixed + 255) & ~(size_t)255;
    unsigned short* Q = (unsigned short*)((char*)d_ws + fixed);

    long freeB = (long)ws_size - (long)fixed;
    int CH = 0;
    if (freeB > 0) {
        long c = freeB / (QC * 2);
        CH = (int)(c > NN ? NN : c);
    }
    bool useQ = (CH >= 1024);
    int NC = 1;
    if (useQ) {
        NC = (NN + CH - 1) / CH;
        CH = (NN + NC - 1) / NC;   // rebalance; CH*QC*2 still fits
    }

    k_w2ext<<<(32 * QC + 255) / 256, 256, 0, stream>>>(enW2, enB2, W2ext);
    k_node_enc<<<NN / 8, 256, 0, stream>>>(nfeats, emb, encW, encB, projW, projB, h);
    k_edge_t<<<NE / 8, 256, 0, stream>>>(efeats, eencW, eencB, enW1, enB1, t);

    int G = 10000;
    if (useQ) {
        hipMemsetAsync(counts, 0, 64 * sizeof(int), stream);
        k_hist<<<(NE + 255) / 256, 256, 0, stream>>>(src, counts, CH);
        k_scan<<<1, 64, 0, stream>>>(counts, offs, cursor, NC);
        k_scatter<<<(NE + 255) / 256, 256, 0, stream>>>(src, cursor, eperm, CH);
        int avg = NE / NC;
        G = (avg + 31) / 32 * 2;
        if (G < 64) G = 64;
        if (G > 10000) G = 10000;
    }

    for (int s = 0; s < 3; ++s) {
        hipMemsetAsync(agg, 0, (size_t)NN * 32 * 4, stream);
        if (useQ) {
            for (int c = 0; c < NC; ++c) {
                int nodeBase = c * CH;
                int nodeEnd = nodeBase + CH; if (nodeEnd > NN) nodeEnd = NN;
                int nb = (nodeEnd - nodeBase + 127) / 128;
                k_Q<<<nb, 256, 0, stream>>>(h, W2ext, Q, nodeBase, nodeEnd);
                k_msgQ<<<G, 256, 0, stream>>>(t, src, dst, eperm, offs, c, nodeBase, Q, agg);
            }
        } else {
            k_msgC<<<NE / 32, 256, 0, stream>>>(t, src, dst, h, W2ext, agg);
        }
        k_gru<<<NN / 32, 256, 0, stream>>>(agg, convB, gruWi, gruWh, gruBi, gruBh, h);
    }
    k_dec<<<NN / 8, 256, 0, stream>>>(h, dW1, db1, da1, dW2, db2, da2, dW3, db3, da3, dW4, db4, out);
}

// Round 3
// 1474.951 us; speedup vs baseline: 4.3837x; 4.3837x over previous
//
#include <hip/hip_runtime.h>
#include <hip/hip_bf16.h>

// MPNN on MI355X.
// msg[e,o] = sum_k t[e,k]*Q[src,k,o] + q0[src,o],  Q'[n] = h[n] @ W2ext
// W2ext[i][k*32+o] = en_W2[k][i*32+o]; cols 1024..1055 hold b2 (per-node bias term q0).
// Q' stored bf16 [CH,1056] in a node-chunked buffer sized to ws_size; edges bucketed by
// src-chunk once per launch via a block-local counting sort (no contended global atomics).

#define NN 100000
#define NE 320000
#define DD 32
#define QC 1056    // 33*32 (32 k-blocks + 1 bias block)
#define HB 128     // histogram blocks
#define EPB ((NE + HB - 1) / HB)   // edges per histogram block (2500)
#define MAXNC 128

__device__ __forceinline__ float bf2f(unsigned short u) {
    return __uint_as_float(((unsigned int)u) << 16);
}
__device__ __forceinline__ unsigned short f2bf(float f) {
    unsigned int x = __float_as_uint(f);
    unsigned int r = (x + 0x7fffu + ((x >> 16) & 1u)) >> 16;
    return (unsigned short)r;
}
__device__ __forceinline__ unsigned int pack2(float lo, float hi) {
    return (unsigned int)f2bf(lo) | ((unsigned int)f2bf(hi) << 16);
}

// ---- build W2ext [32][1056]
__global__ __launch_bounds__(256) void k_w2ext(const float* __restrict__ W2,
                                               const float* __restrict__ b2,
                                               float* __restrict__ W2ext) {
    int idx = blockIdx.x * 256 + threadIdx.x;
    if (idx >= 32 * QC) return;
    int i = idx / QC, c = idx % QC;
    float v;
    if (c < 1024) { int k = c >> 5, o = c & 31; v = W2[k * 1024 + i * 32 + o]; }
    else          { v = b2[i * 32 + (c - 1024)]; }
    W2ext[idx] = v;
}

// ---- node encoder + projection
__global__ __launch_bounds__(256) void k_node_enc(
    const int* __restrict__ nfeats, const float* __restrict__ emb,
    const float* __restrict__ encW, const float* __restrict__ encB,
    const float* __restrict__ projW, const float* __restrict__ projB,
    float* __restrict__ h) {
    __shared__ float sEncW[1024], sProjW[1024], sEncB[32], sProjB[32];
    __shared__ float sEmb[8][33], sNh[8][33];
    int tid = threadIdx.x;
    for (int i = tid; i < 1024; i += 256) { sEncW[i] = encW[i]; sProjW[i] = projW[i]; }
    if (tid < 32) { sEncB[tid] = encB[tid]; sProjB[tid] = projB[tid]; }
    int ln = tid >> 5, o = tid & 31;
    int node = blockIdx.x * 8 + ln;
    int nt = nfeats[node];
    sEmb[ln][o] = fmaxf(emb[nt * DD + o], 0.f);
    __syncthreads();
    float acc = sEncB[o];
    #pragma unroll
    for (int i = 0; i < 32; ++i) acc += sEmb[ln][i] * sEncW[i * 32 + o];
    sNh[ln][o] = fmaxf(acc, 0.f);
    __syncthreads();
    float acc2 = sProjB[o];
    #pragma unroll
    for (int i = 0; i < 32; ++i) acc2 += sNh[ln][i] * sProjW[i * 32 + o];
    h[node * DD + o] = fmaxf(acc2, 0.f);
}

// ---- edge encoder
__global__ __launch_bounds__(256) void k_edge_t(
    const float* __restrict__ efeats,
    const float* __restrict__ eencW, const float* __restrict__ eencB,
    const float* __restrict__ enW1, const float* __restrict__ enB1,
    float* __restrict__ t) {
    __shared__ float sEW[512], sW1[1024], sEB[32], sB1[32];
    __shared__ float sEf[8][17], sEh[8][33];
    int tid = threadIdx.x;
    for (int i = tid; i < 512; i += 256) sEW[i] = eencW[i];
    for (int i = tid; i < 1024; i += 256) sW1[i] = enW1[i];
    if (tid < 32) { sEB[tid] = eencB[tid]; sB1[tid] = enB1[tid]; }
    int ln = tid >> 5, o = tid & 31;
    int e = blockIdx.x * 8 + ln;
    if (o < 16) sEf[ln][o] = efeats[e * 16 + o];
    __syncthreads();
    float acc = sEB[o];
    #pragma unroll
    for (int i = 0; i < 16; ++i) acc += sEf[ln][i] * sEW[i * 32 + o];
    sEh[ln][o] = acc;
    __syncthreads();
    float acc2 = sB1[o];
    #pragma unroll
    for (int i = 0; i < 32; ++i) acc2 += sEh[ln][i] * sW1[i * 32 + o];
    t[e * 32 + o] = fmaxf(acc2, 0.f);
}

// ---- bucketing pass A: per-block LDS histogram -> blockCounts[b][c]
__global__ __launch_bounds__(256) void k_hist2(const int* __restrict__ src,
                                               int* __restrict__ blockCounts,
                                               int CH, int NC) {
    __shared__ int sHist[MAXNC];
    int tid = threadIdx.x, b = blockIdx.x;
    for (int c = tid; c < NC; c += 256) sHist[c] = 0;
    __syncthreads();
    int beg = b * EPB, end = min(beg + EPB, NE);
    for (int e = beg + tid; e < end; e += 256)
        atomicAdd(&sHist[src[e] / CH], 1);
    __syncthreads();
    for (int c = tid; c < NC; c += 256) blockCounts[b * NC + c] = sHist[c];
}

// ---- bucketing pass B: offsets + per-block cursors (single block)
__global__ __launch_bounds__(256) void k_scan2(const int* __restrict__ blockCounts,
                                               int* __restrict__ blockStart,
                                               int* __restrict__ offs, int NC) {
    __shared__ int sTot[MAXNC];
    int tid = threadIdx.x;
    if (tid < NC) {
        int running = 0;
        for (int b = 0; b < HB; ++b) {
            blockStart[b * NC + tid] = running;
            running += blockCounts[b * NC + tid];
        }
        sTot[tid] = running;
    }
    __syncthreads();
    if (tid == 0) {
        int s = 0;
        for (int c = 0; c < NC; ++c) { offs[c] = s; s += sTot[c]; }
        offs[NC] = s;
    }
    __syncthreads();
    for (int idx = tid; idx < HB * NC; idx += 256) {
        int c = idx % NC;
        // add bucket base; offs now in LDS? read from global offs written by tid0
        // (visible after __syncthreads within block)
        blockStart[idx] += offs[c];
    }
}

// ---- bucketing pass C: scatter via LDS cursors
__global__ __launch_bounds__(256) void k_scatter2(const int* __restrict__ src,
                                                  const int* __restrict__ blockStart,
                                                  int* __restrict__ eperm,
                                                  int CH, int NC) {
    __shared__ int sCur[MAXNC];
    int tid = threadIdx.x, b = blockIdx.x;
    for (int c = tid; c < NC; c += 256) sCur[c] = blockStart[b * NC + c];
    __syncthreads();
    int beg = b * EPB, end = min(beg + EPB, NE);
    for (int e = beg + tid; e < end; e += 256) {
        int c = src[e] / CH;
        int pos = atomicAdd(&sCur[c], 1);
        eperm[pos] = e;
    }
}

// ---- Q for a node chunk: Q[n-nodeBase, c] = sum_i h[n,i]*W2ext[i,c]  (bf16)
__global__ __launch_bounds__(256) void k_Q(
    const float* __restrict__ h, const float* __restrict__ W2ext,
    unsigned short* __restrict__ Q, int nodeBase, int nodeEnd) {
    __shared__ float sW[32 * 36];
    int tid = threadIdx.x;
    int m2 = tid >> 2, l4 = tid & 3;
    int n0 = nodeBase + blockIdx.x * 128 + m2;
    int n1 = n0 + 64;
    bool a0 = n0 < nodeEnd, a1 = n1 < nodeEnd;
    float h0[32], h1[32];
    if (a0) {
        const float* hp = h + (size_t)n0 * 32;
        #pragma unroll
        for (int i4 = 0; i4 < 8; ++i4) {
            float4 v = *(const float4*)(hp + i4 * 4);
            h0[i4*4] = v.x; h0[i4*4+1] = v.y; h0[i4*4+2] = v.z; h0[i4*4+3] = v.w;
        }
    } else {
        #pragma unroll
        for (int i = 0; i < 32; ++i) h0[i] = 0.f;
    }
    if (a1) {
        const float* hp = h + (size_t)n1 * 32;
        #pragma unroll
        for (int i4 = 0; i4 < 8; ++i4) {
            float4 v = *(const float4*)(hp + i4 * 4);
            h1[i4*4] = v.x; h1[i4*4+1] = v.y; h1[i4*4+2] = v.z; h1[i4*4+3] = v.w;
        }
    } else {
        #pragma unroll
        for (int i = 0; i < 32; ++i) h1[i] = 0.f;
    }
    unsigned short* q0 = Q + (size_t)(n0 - nodeBase) * QC + l4 * 8;
    unsigned short* q1 = Q + (size_t)(n1 - nodeBase) * QC + l4 * 8;
    for (int cg = 0; cg < 33; ++cg) {
        __syncthreads();
        for (int idx = tid; idx < 1024; idx += 256) {
            int i = idx >> 5, c = idx & 31;
            sW[i * 36 + c] = W2ext[i * QC + cg * 32 + c];
        }
        __syncthreads();
        float acc0[8], acc1[8];
        #pragma unroll
        for (int j = 0; j < 8; ++j) { acc0[j] = 0.f; acc1[j] = 0.f; }
        const float* wp = sW + l4 * 8;
        #pragma unroll 8
        for (int i = 0; i < 32; ++i) {
            float4 wa = *(const float4*)(wp + i * 36);
            float4 wb = *(const float4*)(wp + i * 36 + 4);
            float x0 = h0[i], x1 = h1[i];
            acc0[0] += x0 * wa.x; acc0[1] += x0 * wa.y; acc0[2] += x0 * wa.z; acc0[3] += x0 * wa.w;
            acc0[4] += x0 * wb.x; acc0[5] += x0 * wb.y; acc0[6] += x0 * wb.z; acc0[7] += x0 * wb.w;
            acc1[0] += x1 * wa.x; acc1[1] += x1 * wa.y; acc1[2] += x1 * wa.z; acc1[3] += x1 * wa.w;
            acc1[4] += x1 * wb.x; acc1[5] += x1 * wb.y; acc1[6] += x1 * wb.z; acc1[7] += x1 * wb.w;
        }
        if (a0) {
            uint4 v; v.x = pack2(acc0[0], acc0[1]); v.y = pack2(acc0[2], acc0[3]);
            v.z = pack2(acc0[4], acc0[5]); v.w = pack2(acc0[6], acc0[7]);
            *(uint4*)(q0 + cg * 32) = v;
        }
        if (a1) {
            uint4 v; v.x = pack2(acc1[0], acc1[1]); v.y = pack2(acc1[2], acc1[3]);
            v.z = pack2(acc1[4], acc1[5]); v.w = pack2(acc1[6], acc1[7]);
            *(uint4*)(q1 + cg * 32) = v;
        }
    }
}

// ---- msg + scatter for one chunk's edge bucket
__global__ __launch_bounds__(256) void k_msgQ(
    const float* __restrict__ t, const int* __restrict__ src, const int* __restrict__ dst,
    const int* __restrict__ eperm, const int* __restrict__ offs, int chunk, int nodeBase,
    const unsigned short* __restrict__ Q, float* __restrict__ agg) {
    __shared__ float sT[32][33];
    __shared__ int sRow[32], sDst[32], sEdge[32];
    int beg = offs[chunk], end = offs[chunk + 1];
    int tid = threadIdx.x;
    for (int s0 = beg + blockIdx.x * 32; s0 < end; s0 += gridDim.x * 32) {
        int nact = min(32, end - s0);
        __syncthreads();
        if (tid < 32) {
            int e = (tid < nact) ? eperm[s0 + tid] : -1;
            sEdge[tid] = e;
            sRow[tid] = (e >= 0) ? (src[e] - nodeBase) : 0;
            sDst[tid] = (e >= 0) ? dst[e] : -1;
        }
        __syncthreads();
        for (int idx = tid; idx < (nact << 3); idx += 256) {
            int el = idx >> 3, c4 = (idx & 7) * 4;
            float4 tv = *(const float4*)(t + (size_t)sEdge[el] * 32 + c4);
            sT[el][c4] = tv.x; sT[el][c4+1] = tv.y; sT[el][c4+2] = tv.z; sT[el][c4+3] = tv.w;
        }
        __syncthreads();
        int el = tid >> 3, l8 = tid & 7;
        if (el < nact) {
            const unsigned short* qp = Q + (size_t)sRow[el] * QC + l8 * 4;
            float a0 = 0.f, a1 = 0.f, a2 = 0.f, a3 = 0.f;
            #pragma unroll 8
            for (int k = 0; k < 32; ++k) {
                float tk = sT[el][k];
                ushort4 q = *(const ushort4*)(qp + k * 32);
                a0 += tk * bf2f(q.x); a1 += tk * bf2f(q.y);
                a2 += tk * bf2f(q.z); a3 += tk * bf2f(q.w);
            }
            ushort4 qb = *(const ushort4*)(qp + 1024);
            a0 += bf2f(qb.x); a1 += bf2f(qb.y); a2 += bf2f(qb.z); a3 += bf2f(qb.w);
            float* ap = agg + (size_t)sDst[el] * 32 + l8 * 4;
            atomicAdd(ap + 0, a0); atomicAdd(ap + 1, a1);
            atomicAdd(ap + 2, a2); atomicAdd(ap + 3, a3);
        }
    }
}

// ---- fallback msg (tiny ws): recompute We per edge
__global__ __launch_bounds__(256) void k_msgC(
    const float* __restrict__ t, const int* __restrict__ src, const int* __restrict__ dst,
    const float* __restrict__ h, const float* __restrict__ W2ext, float* __restrict__ agg) {
    __shared__ float sT[32][33], sH[32][33];
    __shared__ int sSrc[32], sDst[32];
    int tid = threadIdx.x;
    int e0 = blockIdx.x * 32;
    if (tid < 32) sSrc[tid] = src[e0 + tid];
    else if (tid < 64) sDst[tid - 32] = dst[e0 + tid - 32];
    __syncthreads();
    for (int idx = tid; idx < 1024; idx += 256) {
        int el = idx >> 5, k = idx & 31;
        sT[el][k] = t[(e0 + el) * 32 + k];
        sH[el][k] = h[(size_t)sSrc[el] * 32 + k];
    }
    __syncthreads();
    int el = tid >> 3, l8 = tid & 7;
    int c0 = l8 * 4;
    float m0 = 0.f, m1 = 0.f, m2 = 0.f, m3 = 0.f;
    for (int i = 0; i < 32; ++i) {
        const float* wrow = W2ext + i * QC;
        float4 wb = *(const float4*)(wrow + 1024 + c0);
        float w0 = wb.x, w1 = wb.y, w2 = wb.z, w3 = wb.w;
        #pragma unroll 8
        for (int k = 0; k < 32; ++k) {
            float tk = sT[el][k];
            float4 w = *(const float4*)(wrow + k * 32 + c0);
            w0 += tk * w.x; w1 += tk * w.y; w2 += tk * w.z; w3 += tk * w.w;
        }
        float hi = sH[el][i];
        m0 += hi * w0; m1 += hi * w1; m2 += hi * w2; m3 += hi * w3;
    }
    float* ap = agg + (size_t)sDst[el] * 32 + c0;
    atomicAdd(ap + 0, m0); atomicAdd(ap + 1, m1);
    atomicAdd(ap + 2, m2); atomicAdd(ap + 3, m3);
}

// ---- GRU step, 32 nodes/block
__global__ __launch_bounds__(256) void k_gru(
    const float* __restrict__ agg, const float* __restrict__ convB,
    const float* __restrict__ Wi, const float* __restrict__ Wh,
    const float* __restrict__ bi, const float* __restrict__ bh,
    float* __restrict__ h) {
    __shared__ float sWi[3072], sWh[3072], sBi[96], sBh[96], sCb[32];
    __shared__ float sX[8][33], sH[8][33];
    int tid = threadIdx.x;
    for (int i = tid; i < 3072; i += 256) { sWi[i] = Wi[i]; sWh[i] = Wh[i]; }
    if (tid < 96) { sBi[tid] = bi[tid]; sBh[tid] = bh[tid]; }
    if (tid < 32) sCb[tid] = convB[tid];
    int ln = tid >> 5, o = tid & 31;
    for (int g = 0; g < 4; ++g) {
        int node = blockIdx.x * 32 + g * 8 + ln;
        float hv = h[node * 32 + o];
        float av = agg[node * 32 + o];
        __syncthreads();
        sX[ln][o] = fmaxf(av + sCb[o], 0.f);
        sH[ln][o] = hv;
        __syncthreads();
        float air = sBi[o], aiz = sBi[o + 32], ain = sBi[o + 64];
        float ahr = sBh[o], ahz = sBh[o + 32], ahn = sBh[o + 64];
        #pragma unroll 8
        for (int i = 0; i < 32; ++i) {
            float x = sX[ln][i], hh = sH[ln][i];
            air += x * sWi[i * 96 + o];      ahr += hh * sWh[i * 96 + o];
            aiz += x * sWi[i * 96 + o + 32]; ahz += hh * sWh[i * 96 + o + 32];
            ain += x * sWi[i * 96 + o + 64]; ahn += hh * sWh[i * 96 + o + 64];
        }
        float r = 1.f / (1.f + __expf(-(air + ahr)));
        float z = 1.f / (1.f + __expf(-(aiz + ahz)));
        float ng = tanhf(ain + r * ahn);
        h[node * 32 + o] = (1.f - z) * ng + z * hv;
    }
}

// ---- decoder
__global__ __launch_bounds__(256) void k_dec(
    const float* __restrict__ h,
    const float* __restrict__ W1, const float* __restrict__ b1, const float* __restrict__ a1,
    const float* __restrict__ W2, const float* __restrict__ b2, const float* __restrict__ a2,
    const float* __restrict__ W3, const float* __restrict__ b3, const float* __restrict__ a3,
    const float* __restrict__ W4, const float* __restrict__ b4,
    float* __restrict__ out) {
    __shared__ float sW1[1024], sW2[1024], sW3[1024], sW4[96];
    __shared__ float sB1[32], sB2[32], sB3[32], sB4[3];
    __shared__ float sYa[8][33], sYb[8][33];
    int tid = threadIdx.x;
    for (int i = tid; i < 1024; i += 256) { sW1[i] = W1[i]; sW2[i] = W2[i]; sW3[i] = W3[i]; }
    if (tid < 96) sW4[tid] = W4[tid];
    if (tid < 32) { sB1[tid] = b1[tid]; sB2[tid] = b2[tid]; sB3[tid] = b3[tid]; }
    if (tid < 3) sB4[tid] = b4[tid];
    float A1 = a1[0], A2 = a2[0], A3 = a3[0];
    int ln = tid >> 5, o = tid & 31;
    int node = blockIdx.x * 8 + ln;
    sYa[ln][o] = h[node * 32 + o];
    __syncthreads();
    float acc = sB1[o];
    #pragma unroll
    for (int i = 0; i < 32; ++i) acc += sYa[ln][i] * sW1[i * 32 + o];
    acc = acc >= 0.f ? acc : A1 * acc;
    sYb[ln][o] = acc;
    __syncthreads();
    acc = sB2[o];
    #pragma unroll
    for (int i = 0; i < 32; ++i) acc += sYb[ln][i] * sW2[i * 32 + o];
    acc = acc >= 0.f ? acc : A2 * acc;
    __syncthreads();
    sYa[ln][o] = acc;
    __syncthreads();
    acc = sB3[o];
    #pragma unroll
    for (int i = 0; i < 32; ++i) acc += sYa[ln][i] * sW3[i * 32 + o];
    acc = acc >= 0.f ? acc : A3 * acc;
    __syncthreads();
    sYb[ln][o] = acc;
    __syncthreads();
    if (o < 3) {
        float r = sB4[o];
        #pragma unroll
        for (int i = 0; i < 32; ++i) r += sYb[ln][i] * sW4[i * 3 + o];
        out[node * 3 + o] = r;
    }
}

extern "C" void kernel_launch(void* const* d_in, const int* in_sizes, int n_in,
                              void* d_out, int out_size, void* d_ws, size_t ws_size,
                              hipStream_t stream) {
    const int*   nfeats = (const int*)d_in[0];
    const float* efeats = (const float*)d_in[1];
    const int*   src    = (const int*)d_in[2];
    const int*   dst    = (const int*)d_in[3];
    const float* emb    = (const float*)d_in[4];
    const float* encW   = (const float*)d_in[5];
    const float* encB   = (const float*)d_in[6];
    const float* eencW  = (const float*)d_in[7];
    const float* eencB  = (const float*)d_in[8];
    const float* projW  = (const float*)d_in[9];
    const float* projB  = (const float*)d_in[10];
    const float* enW1   = (const float*)d_in[11];
    const float* enB1   = (const float*)d_in[12];
    const float* enW2   = (const float*)d_in[13];
    const float* enB2   = (const float*)d_in[14];
    const float* convB  = (const float*)d_in[15];
    const float* gruWi  = (const float*)d_in[16];
    const float* gruWh  = (const float*)d_in[17];
    const float* gruBi  = (const float*)d_in[18];
    const float* gruBh  = (const float*)d_in[19];
    const float* dW1 = (const float*)d_in[20]; const float* db1 = (const float*)d_in[21]; const float* da1 = (const float*)d_in[22];
    const float* dW2 = (const float*)d_in[23]; const float* db2 = (const float*)d_in[24]; const float* da2 = (const float*)d_in[25];
    const float* dW3 = (const float*)d_in[26]; const float* db3 = (const float*)d_in[27]; const float* da3 = (const float*)d_in[28];
    const float* dW4 = (const float*)d_in[29]; const float* db4 = (const float*)d_in[30];
    float* out = (float*)d_out;

    float* h     = (float*)d_ws;                       // NN*32
    float* t     = h + (size_t)NN * 32;                // NE*32
    float* agg   = t + (size_t)NE * 32;                // NN*32
    float* W2ext = agg + (size_t)NN * 32;              // 32*QC
    int* eperm       = (int*)(W2ext + 32 * QC);        // NE
    int* blockCounts = eperm + NE;                     // HB*MAXNC
    int* blockStart  = blockCounts + HB * MAXNC;       // HB*MAXNC
    int* offs        = blockStart + HB * MAXNC;        // MAXNC+1
    size_t fixed = ((char*)(offs + MAXNC + 1) - (char*)d_ws);
    fixed = (fixed + 255) & ~(size_t)255;
    unsigned short* Q = (unsigned short*)((char*)d_ws + fixed);

    long freeB = (long)ws_size - (long)fixed;
    int CH = 0;
    if (freeB > 0) {
        long c = freeB / (QC * 2);
        CH = (int)(c > NN ? NN : c);
    }
    bool useQ = (CH >= 1024);
    int NC = 1;
    if (useQ) {
        NC = (NN + CH - 1) / CH;
        CH = (NN + NC - 1) / NC;   // rebalance; CH*QC*2 still fits
        if (NC > MAXNC) useQ = false;
    }

    k_w2ext<<<(32 * QC + 255) / 256, 256, 0, stream>>>(enW2, enB2, W2ext);
    k_node_enc<<<NN / 8, 256, 0, stream>>>(nfeats, emb, encW, encB, projW, projB, h);
    k_edge_t<<<NE / 8, 256, 0, stream>>>(efeats, eencW, eencB, enW1, enB1, t);

    int G = 10000;
    if (useQ) {
        k_hist2<<<HB, 256, 0, stream>>>(src, blockCounts, CH, NC);
        k_scan2<<<1, 256, 0, stream>>>(blockCounts, blockStart, offs, NC);
        k_scatter2<<<HB, 256, 0, stream>>>(src, blockStart, eperm, CH, NC);
        int avg = NE / NC;
        G = (avg + 31) / 32 * 2;
        if (G < 64) G = 64;
        if (G > 10000) G = 10000;
    }

    for (int s = 0; s < 3; ++s) {
        hipMemsetAsync(agg, 0, (size_t)NN * 32 * 4, stream);
        if (useQ) {
            for (int c = 0; c < NC; ++c) {
                int nodeBase = c * CH;
                int nodeEnd = nodeBase + CH; if (nodeEnd > NN) nodeEnd = NN;
                int nb = (nodeEnd - nodeBase + 127) / 128;
                k_Q<<<nb, 256, 0, stream>>>(h, W2ext, Q, nodeBase, nodeEnd);
                k_msgQ<<<G, 256, 0, stream>>>(t, src, dst, eperm, offs, c, nodeBase, Q, agg);
            }
        } else {
            k_msgC<<<NE / 32, 256, 0, stream>>>(t, src, dst, h, W2ext, agg);
        }
        k_gru<<<NN / 32, 256, 0, stream>>>(agg, convB, gruWi, gruWh, gruBi, gruBh, h);
    }
    k_dec<<<NN / 8, 256, 0, stream>>>(h, dW1, db1, da1, dW2, db2, da2, dW3, db3, da3, dW4, db4, out);
}